// Round 9
// baseline (158.224 us; speedup 1.0000x reference)
//
#include <hip/hip_runtime.h>
#include <hip/hip_bf16.h>

#define TSEQ 2048
#define CDIM 1024
#define NH 16
#define HS 64

typedef __attribute__((ext_vector_type(8))) short bf16x8;
typedef __attribute__((ext_vector_type(4))) float f32x4;
typedef __attribute__((ext_vector_type(16))) float f32x16;

__device__ inline void gload16(const void* g, void* l) {
    __builtin_amdgcn_global_load_lds((const __attribute__((address_space(1))) void*)g,
                                     (__attribute__((address_space(3))) void*)l, 16, 0, 0);
}

__device__ inline unsigned packbf(float a, float b) {
    union { __hip_bfloat162 h; unsigned u; } cv;
    cv.h = __float22bfloat162_rn(make_float2(a, b));
    return cv.u;
}

// ---------- elementwise f32 -> bf16 ----------
__global__ __launch_bounds__(256)
void conv_bf16(const float* __restrict__ in, __hip_bfloat16* __restrict__ out, int n) {
    int i = (blockIdx.x * 256 + threadIdx.x) * 4;
    if (i + 3 < n) {
        float4 v = *(const float4*)(in + i);
        union { ushort4 u; __hip_bfloat16 h[4]; } o;
        o.h[0] = __float2bfloat16(v.x);
        o.h[1] = __float2bfloat16(v.y);
        o.h[2] = __float2bfloat16(v.z);
        o.h[3] = __float2bfloat16(v.w);
        *(ushort4*)((unsigned short*)out + i) = o.u;
    }
}

// ---------- exp(b2) precompute ----------
__global__ __launch_bounds__(256)
void exp_b2(const float* __restrict__ b2, float* __restrict__ eb2, int n) {
    int i = blockIdx.x * 256 + threadIdx.x;
    if (i < n) eb2[i] = __expf(b2[i]);
}

// ---------- tiled transpose (+convert) : in [R][C] f32 -> out [C][R] bf16 ----------
__global__ __launch_bounds__(256)
void transpose_to_bf16(const float* __restrict__ in, __hip_bfloat16* __restrict__ out,
                       int R, int C) {
    __shared__ float t[32][33];
    const int tx = threadIdx.x & 31, ty = threadIdx.x >> 5;  // 32 x 8
    const int r0 = blockIdx.y * 32, c0 = blockIdx.x * 32;
    #pragma unroll
    for (int i = 0; i < 32; i += 8)
        t[ty + i][tx] = in[(size_t)(r0 + ty + i) * C + c0 + tx];
    __syncthreads();
    #pragma unroll
    for (int i = 0; i < 32; i += 8)
        out[(size_t)(c0 + ty + i) * R + r0 + tx] = __float2bfloat16(t[tx][ty + i]);
}

// ---------- fused QV GEMM: [H | V^T] = x @ [W1 | Wv] ----------
// V^T written with sigma-permuted M index (swap bits 2<->3) so the attention
// kernel's PV B-operand lines up with the direct-packed P fragments (no shfl).
__global__ __launch_bounds__(256, 2)
void gemm_qv(const __hip_bfloat16* __restrict__ X, const __hip_bfloat16* __restrict__ W,
             const float* __restrict__ bw1, const float* __restrict__ b1,
             const float* __restrict__ bv, __hip_bfloat16* __restrict__ Hb,
             __hip_bfloat16* __restrict__ Vt, int M)
{
    __shared__ __align__(16) __hip_bfloat16 As[128 * 32];
    __shared__ __align__(16) __hip_bfloat16 Bs[128 * 32];
    const int tid = threadIdx.x, wave = tid >> 6, lane = tid & 63;
    const int wr = wave >> 1, wc = wave & 1, l15 = lane & 15, l4 = lane >> 4;
    const int m0 = blockIdx.y * 128, n0 = blockIdx.x * 128;
    const int K = CDIM;
    const int srow = wave * 32 + (lane >> 2), scol = (lane & 3) * 8;
    const __hip_bfloat16* xg = X + (size_t)(m0 + srow) * K + scol;
    const __hip_bfloat16* wg = W + (size_t)(n0 + srow) * K + scol;
    __hip_bfloat16* la = &As[wave * 32 * 32];
    __hip_bfloat16* lb = &Bs[wave * 32 * 32];

    f32x4 acc[4][4] = {};
    for (int k0 = 0; k0 < K; k0 += 32) {
        __syncthreads();
        gload16(xg + k0, la);
        gload16(xg + k0 + (size_t)16 * K, la + 16 * 32);
        gload16(wg + k0, lb);
        gload16(wg + k0 + (size_t)16 * K, lb + 16 * 32);
        __syncthreads();
        bf16x8 af[4], bfr[4];
        #pragma unroll
        for (int f = 0; f < 4; f++) af[f]  = *(const bf16x8*)&As[(wr * 64 + f * 16 + l15) * 32 + l4 * 8];
        #pragma unroll
        for (int f = 0; f < 4; f++) bfr[f] = *(const bf16x8*)&Bs[(wc * 64 + f * 16 + l15) * 32 + l4 * 8];
        #pragma unroll
        for (int fr = 0; fr < 4; fr++)
            #pragma unroll
            for (int fc = 0; fc < 4; fc++)
                acc[fr][fc] = __builtin_amdgcn_mfma_f32_16x16x32_bf16(af[fr], bfr[fc], acc[fr][fc], 0, 0, 0);
    }

    const bool isH = (n0 < CDIM);
    const int sl4 = ((l4 & 1) << 1) | (l4 >> 1);   // sigma: swap m-bits 2,3
    #pragma unroll
    for (int fc = 0; fc < 4; fc++) {
        const int col = n0 + wc * 64 + fc * 16 + l15;
        if (isH) {
            const float bias = bw1[col] + b1[col & (HS - 1)];
            #pragma unroll
            for (int fr = 0; fr < 4; fr++)
                #pragma unroll
                for (int r = 0; r < 4; r++) {
                    const int row = m0 + wr * 64 + fr * 16 + l4 * 4 + r;
                    Hb[(size_t)row * CDIM + col] = __float2bfloat16(fmaxf(acc[fr][fc][r] + bias, 0.f));
                }
        } else {
            const int c2 = col - CDIM;
            const float bias = bv[c2];
            #pragma unroll
            for (int fr = 0; fr < 4; fr++) {
                const int rowb = m0 + wr * 64 + fr * 16 + sl4 * 4;
                union { ushort4 u; __hip_bfloat16 h[4]; } o;
                #pragma unroll
                for (int r = 0; r < 4; r++) o.h[r] = __float2bfloat16(acc[fr][fc][r] + bias);
                *(ushort4*)(Vt + (size_t)c2 * M + rowb) = o.u;
            }
        }
    }
}

// ---------- projection GEMM: out = Y @ Wp + bp (f32 out) ----------
__global__ __launch_bounds__(256, 2)
void gemm_proj(const __hip_bfloat16* __restrict__ X, const __hip_bfloat16* __restrict__ Wt,
               const float* __restrict__ bN, float* __restrict__ Out, int M)
{
    __shared__ __align__(16) __hip_bfloat16 As[128 * 32];
    __shared__ __align__(16) __hip_bfloat16 Bs[128 * 32];
    const int tid = threadIdx.x, wave = tid >> 6, lane = tid & 63;
    const int wr = wave >> 1, wc = wave & 1, l15 = lane & 15, l4 = lane >> 4;
    const int m0 = blockIdx.y * 128, n0 = blockIdx.x * 128;
    const int K = CDIM;
    const int srow = wave * 32 + (lane >> 2), scol = (lane & 3) * 8;
    const __hip_bfloat16* xg = X + (size_t)(m0 + srow) * K + scol;
    const __hip_bfloat16* wg = Wt + (size_t)(n0 + srow) * K + scol;
    __hip_bfloat16* la = &As[wave * 32 * 32];
    __hip_bfloat16* lb = &Bs[wave * 32 * 32];

    f32x4 acc[4][4] = {};
    for (int k0 = 0; k0 < K; k0 += 32) {
        __syncthreads();
        gload16(xg + k0, la);
        gload16(xg + k0 + (size_t)16 * K, la + 16 * 32);
        gload16(wg + k0, lb);
        gload16(wg + k0 + (size_t)16 * K, lb + 16 * 32);
        __syncthreads();
        bf16x8 af[4], bfr[4];
        #pragma unroll
        for (int f = 0; f < 4; f++) af[f]  = *(const bf16x8*)&As[(wr * 64 + f * 16 + l15) * 32 + l4 * 8];
        #pragma unroll
        for (int f = 0; f < 4; f++) bfr[f] = *(const bf16x8*)&Bs[(wc * 64 + f * 16 + l15) * 32 + l4 * 8];
        #pragma unroll
        for (int fr = 0; fr < 4; fr++)
            #pragma unroll
            for (int fc = 0; fc < 4; fc++)
                acc[fr][fc] = __builtin_amdgcn_mfma_f32_16x16x32_bf16(af[fr], bfr[fc], acc[fr][fc], 0, 0, 0);
    }

    #pragma unroll
    for (int fc = 0; fc < 4; fc++) {
        const int col = n0 + wc * 64 + fc * 16 + l15;
        const float bias = bN[col];
        #pragma unroll
        for (int fr = 0; fr < 4; fr++)
            #pragma unroll
            for (int r = 0; r < 4; r++) {
                const int row = m0 + wr * 64 + fr * 16 + l4 * 4 + r;
                Out[(size_t)row * CDIM + col] = acc[fr][fc][r] + bias;
            }
    }
}

// ---------- fused synthesizer attention v5: LDS-free, barrier-free main loop ----
// K (w2t [T][HS]) and V (Vt [C][M], sigma-permuted t) are ALREADY in MFMA
// fragment layout in memory: each lane's fragment is one contiguous 16B global
// load (L2-resident). No staging, no block barriers, no bank conflicts.
// 4 waves x 32 q rows; each wave free-runs its causal k-range.
__global__ __launch_bounds__(256, 2)
void attn_mfma5(const __hip_bfloat16* __restrict__ H, const __hip_bfloat16* __restrict__ w2t,
                const __hip_bfloat16* __restrict__ Vt, const float* __restrict__ eb2,
                __hip_bfloat16* __restrict__ Y, int M)
{
    __shared__ float Ls[4 * 32];

    const int tid = threadIdx.x;
    const int w = tid >> 6, lane = tid & 63;
    const int l31 = lane & 31, hi = lane >> 5;
    const int h = blockIdx.y, b = blockIdx.z;
    const int u = (blockIdx.x + blockIdx.y) & 15;
    const int qb = b ? (15 - u) : u;        // causal load-balance pairing
    const int q0 = qb * 128;
    const int qw = q0 + w * 32;             // this wave's first q row

    // H fragments (B-operand: col=lane&31=q, k=hi*8+j), in registers
    bf16x8 hf[4];
    {
        const size_t row = (size_t)(b * TSEQ + qw + l31);
        #pragma unroll
        for (int kk = 0; kk < 4; kk++)
            hf[kk] = *(const bf16x8*)(H + row * CDIM + h * HS + kk * 16 + hi * 8);
    }

    // per-lane fragment base pointers
    const __hip_bfloat16* kbase = w2t + (size_t)l31 * HS + hi * 8;               // + (k0+tf*32)*HS + kk*16
    const __hip_bfloat16* vbase = Vt + (size_t)(h * HS + l31) * M + b * TSEQ + hi * 8;  // + df*32*M + k0 + ks*16

    f32x16 yacc[2] = {};
    float lsum = 0.f;
    const int lastkt = (qw + 31) >> 6;      // inclusive causal bound for this wave

    for (int kt = 0; kt <= lastkt; kt++) {
        const int k0 = kt * 64;
        const bool nomask = (k0 + 63 <= qw);
        bf16x8 pa[4];
        #pragma unroll
        for (int tf = 0; tf < 2; tf++) {
            float4 eb[4];
            #pragma unroll
            for (int g = 0; g < 4; g++)
                eb[g] = *(const float4*)(eb2 + k0 + tf * 32 + g * 8 + hi * 4);
            f32x16 st = {};
            #pragma unroll
            for (int kk = 0; kk < 4; kk++) {
                bf16x8 kf = *(const bf16x8*)(kbase + (size_t)(k0 + tf * 32) * HS + kk * 16);
                st = __builtin_amdgcn_mfma_f32_32x32x16_bf16(kf, hf[kk], st, 0, 0, 0);
            }
            const int qg = qw + l31;
            float p[16];
            #pragma unroll
            for (int r = 0; r < 16; r++) {
                float e = __expf(st[r]) * ((const float*)&eb[r >> 2])[r & 3];
                if (!nomask) {
                    const int tg = k0 + tf * 32 + (r & 3) + 8 * (r >> 2) + 4 * hi;
                    if (tg > qg) e = 0.f;
                }
                p[r] = e;
                lsum += e;
            }
            // direct pack: A-slot j of chunk ks=2tf+m <- p[8m+j] (sigma'd V aligns)
            #pragma unroll
            for (int m = 0; m < 2; m++) {
                union { unsigned d[4]; bf16x8 v; } pk;
                #pragma unroll
                for (int dw = 0; dw < 4; dw++)
                    pk.d[dw] = packbf(p[8 * m + 2 * dw], p[8 * m + 2 * dw + 1]);
                pa[tf * 2 + m] = pk.v;
            }
        }
        // PV: Y += P @ V_tile (V fragments direct from global)
        #pragma unroll
        for (int ks = 0; ks < 4; ks++) {
            #pragma unroll
            for (int df = 0; df < 2; df++) {
                bf16x8 vf = *(const bf16x8*)(vbase + (size_t)(df * 32) * M + k0 + ks * 16);
                yacc[df] = __builtin_amdgcn_mfma_f32_32x32x16_bf16(pa[ks], vf, yacc[df], 0, 0, 0);
            }
        }
    }

    // combine the two k-halves (hi 0/1) of each q-row sum, publish per-wave
    lsum += __shfl_xor(lsum, 32);
    if (hi == 0) Ls[w * 32 + l31] = lsum;
    __syncthreads();

    #pragma unroll
    for (int g = 0; g < 4; g++) {
        float4 lv = *(const float4*)&Ls[w * 32 + g * 8 + hi * 4];
        #pragma unroll
        for (int df = 0; df < 2; df++)
            #pragma unroll
            for (int rr = 0; rr < 4; rr++) {
                const float v = yacc[df][g * 4 + rr] / ((const float*)&lv)[rr];
                const size_t row = (size_t)(b * TSEQ + qw + 8 * g + 4 * hi + rr);
                Y[row * CDIM + h * HS + df * 32 + l31] = __float2bfloat16(v);
            }
    }
}

extern "C" void kernel_launch(void* const* d_in, const int* in_sizes, int n_in,
                              void* d_out, int out_size, void* d_ws, size_t ws_size,
                              hipStream_t stream) {
    const float* x   = (const float*)d_in[0];
    const float* W1  = (const float*)d_in[1];
    const float* bw1 = (const float*)d_in[2];
    const float* b1  = (const float*)d_in[3];
    const float* w2  = (const float*)d_in[4];
    const float* b2  = (const float*)d_in[5];
    const float* Wv  = (const float*)d_in[6];
    const float* bv  = (const float*)d_in[7];
    const float* Wp  = (const float*)d_in[8];
    const float* bp  = (const float*)d_in[9];
    float* out = (float*)d_out;

    const int B = in_sizes[0] / (TSEQ * CDIM);   // 2
    const int M = B * TSEQ;                      // 4096
    const size_t MC = (size_t)M * CDIM;          // 4M
    const size_t WC = (size_t)CDIM * CDIM;       // 1M

    __hip_bfloat16* xb  = (__hip_bfloat16*)d_ws;
    __hip_bfloat16* Wqv = xb  + MC;              // [2048][1024]: W1t then Wvt
    __hip_bfloat16* Wpt = Wqv + 2 * WC;
    __hip_bfloat16* w2t = Wpt + WC;              // [T][HS]
    __hip_bfloat16* Hb  = w2t + (size_t)TSEQ * HS;
    __hip_bfloat16* Vtb = Hb  + MC;              // [C][M], sigma-permuted M
    __hip_bfloat16* Yb  = Vtb + MC;
    float*          eb2 = (float*)(Yb + MC);     // exp(b2), T floats

    dim3 blk(256);
    conv_bf16<<<dim3((unsigned)(MC / 1024)), blk, 0, stream>>>(x, xb, (int)MC);
    exp_b2<<<dim3(TSEQ / 256), blk, 0, stream>>>(b2, eb2, TSEQ);
    transpose_to_bf16<<<dim3(32, 32), blk, 0, stream>>>(W1, Wqv, CDIM, CDIM);
    transpose_to_bf16<<<dim3(32, 32), blk, 0, stream>>>(Wv, Wqv + WC, CDIM, CDIM);
    transpose_to_bf16<<<dim3(32, 32), blk, 0, stream>>>(Wp, Wpt, CDIM, CDIM);
    transpose_to_bf16<<<dim3(TSEQ / 32, HS / 32), blk, 0, stream>>>(w2, w2t, HS, TSEQ);

    gemm_qv<<<dim3(16, M / 128), blk, 0, stream>>>(xb, Wqv, bw1, b1, bv, Hb, Vtb, M);

    attn_mfma5<<<dim3(16, NH, B), blk, 0, stream>>>(Hb, w2t, Vtb, eb2, Yb, M);

    gemm_proj<<<dim3(8, M / 128), blk, 0, stream>>>(Yb, Wpt, bp, out, M);
}

// Round 10
// 157.108 us; speedup vs baseline: 1.0071x; 1.0071x over previous
//
#include <hip/hip_runtime.h>
#include <hip/hip_bf16.h>

#define TSEQ 2048
#define CDIM 1024
#define NH 16
#define HS 64

typedef __attribute__((ext_vector_type(8))) short bf16x8;
typedef __attribute__((ext_vector_type(4))) float f32x4;
typedef __attribute__((ext_vector_type(16))) float f32x16;

__device__ inline void gload16(const void* g, void* l) {
    __builtin_amdgcn_global_load_lds((const __attribute__((address_space(1))) void*)g,
                                     (__attribute__((address_space(3))) void*)l, 16, 0, 0);
}

__device__ inline unsigned packbf(float a, float b) {
    union { __hip_bfloat162 h; unsigned u; } cv;
    cv.h = __float22bfloat162_rn(make_float2(a, b));
    return cv.u;
}

// ---------- elementwise f32 -> bf16 ----------
__global__ __launch_bounds__(256)
void conv_bf16(const float* __restrict__ in, __hip_bfloat16* __restrict__ out, int n) {
    int i = (blockIdx.x * 256 + threadIdx.x) * 4;
    if (i + 3 < n) {
        float4 v = *(const float4*)(in + i);
        union { ushort4 u; __hip_bfloat16 h[4]; } o;
        o.h[0] = __float2bfloat16(v.x);
        o.h[1] = __float2bfloat16(v.y);
        o.h[2] = __float2bfloat16(v.z);
        o.h[3] = __float2bfloat16(v.w);
        *(ushort4*)((unsigned short*)out + i) = o.u;
    }
}

// ---------- exp(b2) precompute ----------
__global__ __launch_bounds__(256)
void exp_b2(const float* __restrict__ b2, float* __restrict__ eb2, int n) {
    int i = blockIdx.x * 256 + threadIdx.x;
    if (i < n) eb2[i] = __expf(b2[i]);
}

// ---------- tiled transpose (+convert) : in [R][C] f32 -> out [C][R] bf16 ----------
__global__ __launch_bounds__(256)
void transpose_to_bf16(const float* __restrict__ in, __hip_bfloat16* __restrict__ out,
                       int R, int C) {
    __shared__ float t[32][33];
    const int tx = threadIdx.x & 31, ty = threadIdx.x >> 5;  // 32 x 8
    const int r0 = blockIdx.y * 32, c0 = blockIdx.x * 32;
    #pragma unroll
    for (int i = 0; i < 32; i += 8)
        t[ty + i][tx] = in[(size_t)(r0 + ty + i) * C + c0 + tx];
    __syncthreads();
    #pragma unroll
    for (int i = 0; i < 32; i += 8)
        out[(size_t)(c0 + ty + i) * R + r0 + tx] = __float2bfloat16(t[tx][ty + i]);
}

// ---------- fused 3x 1024x1024 transpose (W1, Wv, Wp) ----------
__global__ __launch_bounds__(256)
void transpose3_to_bf16(const float* __restrict__ W1, const float* __restrict__ Wv,
                        const float* __restrict__ Wp, __hip_bfloat16* __restrict__ o1,
                        __hip_bfloat16* __restrict__ o2, __hip_bfloat16* __restrict__ o3) {
    __shared__ float t[32][33];
    const float* in = blockIdx.z == 0 ? W1 : (blockIdx.z == 1 ? Wv : Wp);
    __hip_bfloat16* out = blockIdx.z == 0 ? o1 : (blockIdx.z == 1 ? o2 : o3);
    const int tx = threadIdx.x & 31, ty = threadIdx.x >> 5;
    const int r0 = blockIdx.y * 32, c0 = blockIdx.x * 32;
    #pragma unroll
    for (int i = 0; i < 32; i += 8)
        t[ty + i][tx] = in[(size_t)(r0 + ty + i) * CDIM + c0 + tx];
    __syncthreads();
    #pragma unroll
    for (int i = 0; i < 32; i += 8)
        out[(size_t)(c0 + ty + i) * CDIM + r0 + tx] = __float2bfloat16(t[tx][ty + i]);
}

// ---------- fused QV GEMM: [H | V^T] = x @ [W1 | Wv] ----------
// V^T written with sigma-permuted M index (swap bits 2<->3) so the attention
// kernel's PV B-operand lines up with the direct-packed P fragments (no shfl).
__global__ __launch_bounds__(256, 2)
void gemm_qv(const __hip_bfloat16* __restrict__ X, const __hip_bfloat16* __restrict__ W,
             const float* __restrict__ bw1, const float* __restrict__ b1,
             const float* __restrict__ bv, __hip_bfloat16* __restrict__ Hb,
             __hip_bfloat16* __restrict__ Vt, int M)
{
    __shared__ __align__(16) __hip_bfloat16 As[128 * 32];
    __shared__ __align__(16) __hip_bfloat16 Bs[128 * 32];
    const int tid = threadIdx.x, wave = tid >> 6, lane = tid & 63;
    const int wr = wave >> 1, wc = wave & 1, l15 = lane & 15, l4 = lane >> 4;
    const int m0 = blockIdx.y * 128, n0 = blockIdx.x * 128;
    const int K = CDIM;
    const int srow = wave * 32 + (lane >> 2), scol = (lane & 3) * 8;
    const __hip_bfloat16* xg = X + (size_t)(m0 + srow) * K + scol;
    const __hip_bfloat16* wg = W + (size_t)(n0 + srow) * K + scol;
    __hip_bfloat16* la = &As[wave * 32 * 32];
    __hip_bfloat16* lb = &Bs[wave * 32 * 32];

    f32x4 acc[4][4] = {};
    for (int k0 = 0; k0 < K; k0 += 32) {
        __syncthreads();
        gload16(xg + k0, la);
        gload16(xg + k0 + (size_t)16 * K, la + 16 * 32);
        gload16(wg + k0, lb);
        gload16(wg + k0 + (size_t)16 * K, lb + 16 * 32);
        __syncthreads();
        bf16x8 af[4], bfr[4];
        #pragma unroll
        for (int f = 0; f < 4; f++) af[f]  = *(const bf16x8*)&As[(wr * 64 + f * 16 + l15) * 32 + l4 * 8];
        #pragma unroll
        for (int f = 0; f < 4; f++) bfr[f] = *(const bf16x8*)&Bs[(wc * 64 + f * 16 + l15) * 32 + l4 * 8];
        #pragma unroll
        for (int fr = 0; fr < 4; fr++)
            #pragma unroll
            for (int fc = 0; fc < 4; fc++)
                acc[fr][fc] = __builtin_amdgcn_mfma_f32_16x16x32_bf16(af[fr], bfr[fc], acc[fr][fc], 0, 0, 0);
    }

    const bool isH = (n0 < CDIM);
    const int sl4 = ((l4 & 1) << 1) | (l4 >> 1);   // sigma: swap m-bits 2,3
    #pragma unroll
    for (int fc = 0; fc < 4; fc++) {
        const int col = n0 + wc * 64 + fc * 16 + l15;
        if (isH) {
            const float bias = bw1[col] + b1[col & (HS - 1)];
            #pragma unroll
            for (int fr = 0; fr < 4; fr++)
                #pragma unroll
                for (int r = 0; r < 4; r++) {
                    const int row = m0 + wr * 64 + fr * 16 + l4 * 4 + r;
                    Hb[(size_t)row * CDIM + col] = __float2bfloat16(fmaxf(acc[fr][fc][r] + bias, 0.f));
                }
        } else {
            const int c2 = col - CDIM;
            const float bias = bv[c2];
            #pragma unroll
            for (int fr = 0; fr < 4; fr++) {
                const int rowb = m0 + wr * 64 + fr * 16 + sl4 * 4;
                union { ushort4 u; __hip_bfloat16 h[4]; } o;
                #pragma unroll
                for (int r = 0; r < 4; r++) o.h[r] = __float2bfloat16(acc[fr][fc][r] + bias);
                *(ushort4*)(Vt + (size_t)c2 * M + rowb) = o.u;
            }
        }
    }
}

// ---------- projection GEMM: out = Y @ Wp + bp (f32 out) ----------
__global__ __launch_bounds__(256, 2)
void gemm_proj(const __hip_bfloat16* __restrict__ X, const __hip_bfloat16* __restrict__ Wt,
               const float* __restrict__ bN, float* __restrict__ Out, int M)
{
    __shared__ __align__(16) __hip_bfloat16 As[128 * 32];
    __shared__ __align__(16) __hip_bfloat16 Bs[128 * 32];
    const int tid = threadIdx.x, wave = tid >> 6, lane = tid & 63;
    const int wr = wave >> 1, wc = wave & 1, l15 = lane & 15, l4 = lane >> 4;
    const int m0 = blockIdx.y * 128, n0 = blockIdx.x * 128;
    const int K = CDIM;
    const int srow = wave * 32 + (lane >> 2), scol = (lane & 3) * 8;
    const __hip_bfloat16* xg = X + (size_t)(m0 + srow) * K + scol;
    const __hip_bfloat16* wg = Wt + (size_t)(n0 + srow) * K + scol;
    __hip_bfloat16* la = &As[wave * 32 * 32];
    __hip_bfloat16* lb = &Bs[wave * 32 * 32];

    f32x4 acc[4][4] = {};
    for (int k0 = 0; k0 < K; k0 += 32) {
        __syncthreads();
        gload16(xg + k0, la);
        gload16(xg + k0 + (size_t)16 * K, la + 16 * 32);
        gload16(wg + k0, lb);
        gload16(wg + k0 + (size_t)16 * K, lb + 16 * 32);
        __syncthreads();
        bf16x8 af[4], bfr[4];
        #pragma unroll
        for (int f = 0; f < 4; f++) af[f]  = *(const bf16x8*)&As[(wr * 64 + f * 16 + l15) * 32 + l4 * 8];
        #pragma unroll
        for (int f = 0; f < 4; f++) bfr[f] = *(const bf16x8*)&Bs[(wc * 64 + f * 16 + l15) * 32 + l4 * 8];
        #pragma unroll
        for (int fr = 0; fr < 4; fr++)
            #pragma unroll
            for (int fc = 0; fc < 4; fc++)
                acc[fr][fc] = __builtin_amdgcn_mfma_f32_16x16x32_bf16(af[fr], bfr[fc], acc[fr][fc], 0, 0, 0);
    }

    #pragma unroll
    for (int fc = 0; fc < 4; fc++) {
        const int col = n0 + wc * 64 + fc * 16 + l15;
        const float bias = bN[col];
        #pragma unroll
        for (int fr = 0; fr < 4; fr++)
            #pragma unroll
            for (int r = 0; r < 4; r++) {
                const int row = m0 + wr * 64 + fr * 16 + l4 * 4 + r;
                Out[(size_t)row * CDIM + col] = acc[fr][fc][r] + bias;
            }
    }
}

// ---------- fused synthesizer attention v6: balanced, LDS/barrier-free ----------
// Block = 512 threads (8 waves) per (q-tile-pair i, h, b): waves 0-3 own q-tile
// i, waves 4-7 own q-tile 15-i (32 q rows each). Grid = 256 = 1 block/CU; waves
// w and w+4 share a SIMD and their causal iteration counts sum to ~33 by
// construction -> deterministic per-SIMD balance, zero tail. K (w2t) and V
// (sigma-permuted Vt) are read as direct 16B fragment loads from global (L2).
__global__ __launch_bounds__(512, 2)
void attn_mfma6(const __hip_bfloat16* __restrict__ H, const __hip_bfloat16* __restrict__ w2t,
                const __hip_bfloat16* __restrict__ Vt, const float* __restrict__ eb2,
                __hip_bfloat16* __restrict__ Y, int M)
{
    __shared__ float Ls[8 * 32];

    const int tid = threadIdx.x;
    const int w = tid >> 6, lane = tid & 63;
    const int l31 = lane & 31, hi = lane >> 5;
    const int h = blockIdx.y, b = blockIdx.z;
    const int i = blockIdx.x;                       // pair index 0..7
    const int qtile = (w >> 2) ? (15 - i) : i;      // waves 0-3: i, 4-7: 15-i
    const int qw = qtile * 128 + (w & 3) * 32;      // this wave's first q row

    // H fragments (B-operand: col=lane&31=q, k=hi*8+j), in registers
    bf16x8 hf[4];
    {
        const size_t row = (size_t)(b * TSEQ + qw + l31);
        #pragma unroll
        for (int kk = 0; kk < 4; kk++)
            hf[kk] = *(const bf16x8*)(H + row * CDIM + h * HS + kk * 16 + hi * 8);
    }

    // per-lane fragment base pointers
    const __hip_bfloat16* kbase = w2t + (size_t)l31 * HS + hi * 8;
    const __hip_bfloat16* vbase = Vt + (size_t)(h * HS + l31) * M + b * TSEQ + hi * 8;

    f32x16 yacc[2] = {};
    float lsum = 0.f;
    const int lastkt = (qw + 31) >> 6;      // inclusive causal bound for this wave

    for (int kt = 0; kt <= lastkt; kt++) {
        const int k0 = kt * 64;
        const bool nomask = (k0 + 63 <= qw);
        bf16x8 pa[4];
        #pragma unroll
        for (int tf = 0; tf < 2; tf++) {
            float4 eb[4];
            #pragma unroll
            for (int g = 0; g < 4; g++)
                eb[g] = *(const float4*)(eb2 + k0 + tf * 32 + g * 8 + hi * 4);
            f32x16 st = {};
            #pragma unroll
            for (int kk = 0; kk < 4; kk++) {
                bf16x8 kf = *(const bf16x8*)(kbase + (size_t)(k0 + tf * 32) * HS + kk * 16);
                st = __builtin_amdgcn_mfma_f32_32x32x16_bf16(kf, hf[kk], st, 0, 0, 0);
            }
            const int qg = qw + l31;
            float p[16];
            #pragma unroll
            for (int r = 0; r < 16; r++) {
                float e = __expf(st[r]) * ((const float*)&eb[r >> 2])[r & 3];
                if (!nomask) {
                    const int tg = k0 + tf * 32 + (r & 3) + 8 * (r >> 2) + 4 * hi;
                    if (tg > qg) e = 0.f;
                }
                p[r] = e;
                lsum += e;
            }
            // direct pack: A-slot j of chunk ks=2tf+m <- p[8m+j] (sigma'd V aligns)
            #pragma unroll
            for (int m = 0; m < 2; m++) {
                union { unsigned d[4]; bf16x8 v; } pk;
                #pragma unroll
                for (int dw = 0; dw < 4; dw++)
                    pk.d[dw] = packbf(p[8 * m + 2 * dw], p[8 * m + 2 * dw + 1]);
                pa[tf * 2 + m] = pk.v;
            }
        }
        // PV: Y += P @ V_tile (V fragments direct from global)
        #pragma unroll
        for (int ks = 0; ks < 4; ks++) {
            #pragma unroll
            for (int df = 0; df < 2; df++) {
                bf16x8 vf = *(const bf16x8*)(vbase + (size_t)(df * 32) * M + k0 + ks * 16);
                yacc[df] = __builtin_amdgcn_mfma_f32_32x32x16_bf16(pa[ks], vf, yacc[df], 0, 0, 0);
            }
        }
    }

    // combine the two k-halves (hi 0/1) of each q-row sum, publish per-wave
    lsum += __shfl_xor(lsum, 32);
    if (hi == 0) Ls[w * 32 + l31] = lsum;
    __syncthreads();

    #pragma unroll
    for (int g = 0; g < 4; g++) {
        float4 lv = *(const float4*)&Ls[w * 32 + g * 8 + hi * 4];
        #pragma unroll
        for (int df = 0; df < 2; df++)
            #pragma unroll
            for (int rr = 0; rr < 4; rr++) {
                const float v = yacc[df][g * 4 + rr] / ((const float*)&lv)[rr];
                const size_t row = (size_t)(b * TSEQ + qw + 8 * g + 4 * hi + rr);
                Y[row * CDIM + h * HS + df * 32 + l31] = __float2bfloat16(v);
            }
    }
}

extern "C" void kernel_launch(void* const* d_in, const int* in_sizes, int n_in,
                              void* d_out, int out_size, void* d_ws, size_t ws_size,
                              hipStream_t stream) {
    const float* x   = (const float*)d_in[0];
    const float* W1  = (const float*)d_in[1];
    const float* bw1 = (const float*)d_in[2];
    const float* b1  = (const float*)d_in[3];
    const float* w2  = (const float*)d_in[4];
    const float* b2  = (const float*)d_in[5];
    const float* Wv  = (const float*)d_in[6];
    const float* bv  = (const float*)d_in[7];
    const float* Wp  = (const float*)d_in[8];
    const float* bp  = (const float*)d_in[9];
    float* out = (float*)d_out;

    const int B = in_sizes[0] / (TSEQ * CDIM);   // 2
    const int M = B * TSEQ;                      // 4096
    const size_t MC = (size_t)M * CDIM;          // 4M
    const size_t WC = (size_t)CDIM * CDIM;       // 1M

    __hip_bfloat16* xb  = (__hip_bfloat16*)d_ws;
    __hip_bfloat16* Wqv = xb  + MC;              // [2048][1024]: W1t then Wvt
    __hip_bfloat16* Wpt = Wqv + 2 * WC;
    __hip_bfloat16* w2t = Wpt + WC;              // [T][HS]
    __hip_bfloat16* Hb  = w2t + (size_t)TSEQ * HS;
    __hip_bfloat16* Vtb = Hb  + MC;              // [C][M], sigma-permuted M
    __hip_bfloat16* Yb  = Vtb + MC;
    float*          eb2 = (float*)(Yb + MC);     // exp(b2), T floats

    dim3 blk(256);
    conv_bf16<<<dim3((unsigned)(MC / 1024)), blk, 0, stream>>>(x, xb, (int)MC);
    exp_b2<<<dim3(TSEQ / 256), blk, 0, stream>>>(b2, eb2, TSEQ);
    transpose3_to_bf16<<<dim3(32, 32, 3), blk, 0, stream>>>(W1, Wv, Wp, Wqv, Wqv + WC, Wpt);
    transpose_to_bf16<<<dim3(TSEQ / 32, HS / 32), blk, 0, stream>>>(w2, w2t, HS, TSEQ);

    gemm_qv<<<dim3(16, M / 128), blk, 0, stream>>>(xb, Wqv, bw1, b1, bv, Hb, Vtb, M);

    attn_mfma6<<<dim3(8, NH, B), dim3(512), 0, stream>>>(Hb, w2t, Vtb, eb2, Yb, M);

    gemm_proj<<<dim3(8, M / 128), blk, 0, stream>>>(Yb, Wpt, bp, out, M);
}

// Round 11
// 152.310 us; speedup vs baseline: 1.0388x; 1.0315x over previous
//
#include <hip/hip_runtime.h>
#include <hip/hip_bf16.h>

#define TSEQ 2048
#define CDIM 1024
#define NH 16
#define HS 64

typedef __attribute__((ext_vector_type(8))) short bf16x8;
typedef __attribute__((ext_vector_type(4))) float f32x4;
typedef __attribute__((ext_vector_type(16))) float f32x16;

__device__ inline void gload16(const void* g, void* l) {
    __builtin_amdgcn_global_load_lds((const __attribute__((address_space(1))) void*)g,
                                     (__attribute__((address_space(3))) void*)l, 16, 0, 0);
}

__device__ inline unsigned packbf(float a, float b) {
    union { __hip_bfloat162 h; unsigned u; } cv;
    cv.h = __float22bfloat162_rn(make_float2(a, b));
    return cv.u;
}

// ---------- elementwise f32 -> bf16 ----------
__global__ __launch_bounds__(256)
void conv_bf16(const float* __restrict__ in, __hip_bfloat16* __restrict__ out, int n) {
    int i = (blockIdx.x * 256 + threadIdx.x) * 4;
    if (i + 3 < n) {
        float4 v = *(const float4*)(in + i);
        union { ushort4 u; __hip_bfloat16 h[4]; } o;
        o.h[0] = __float2bfloat16(v.x);
        o.h[1] = __float2bfloat16(v.y);
        o.h[2] = __float2bfloat16(v.z);
        o.h[3] = __float2bfloat16(v.w);
        *(ushort4*)((unsigned short*)out + i) = o.u;
    }
}

// ---------- exp(b2) precompute ----------
__global__ __launch_bounds__(256)
void exp_b2(const float* __restrict__ b2, float* __restrict__ eb2, int n) {
    int i = blockIdx.x * 256 + threadIdx.x;
    if (i < n) eb2[i] = __expf(b2[i]);
}

// ---------- tiled transpose (+convert) : in [R][C] f32 -> out [C][R] bf16 ----------
__global__ __launch_bounds__(256)
void transpose_to_bf16(const float* __restrict__ in, __hip_bfloat16* __restrict__ out,
                       int R, int C) {
    __shared__ float t[32][33];
    const int tx = threadIdx.x & 31, ty = threadIdx.x >> 5;  // 32 x 8
    const int r0 = blockIdx.y * 32, c0 = blockIdx.x * 32;
    #pragma unroll
    for (int i = 0; i < 32; i += 8)
        t[ty + i][tx] = in[(size_t)(r0 + ty + i) * C + c0 + tx];
    __syncthreads();
    #pragma unroll
    for (int i = 0; i < 32; i += 8)
        out[(size_t)(c0 + ty + i) * R + r0 + tx] = __float2bfloat16(t[tx][ty + i]);
}

// ---------- fused 3x 1024x1024 transpose (W1, Wv, Wp) ----------
__global__ __launch_bounds__(256)
void transpose3_to_bf16(const float* __restrict__ W1, const float* __restrict__ Wv,
                        const float* __restrict__ Wp, __hip_bfloat16* __restrict__ o1,
                        __hip_bfloat16* __restrict__ o2, __hip_bfloat16* __restrict__ o3) {
    __shared__ float t[32][33];
    const float* in = blockIdx.z == 0 ? W1 : (blockIdx.z == 1 ? Wv : Wp);
    __hip_bfloat16* out = blockIdx.z == 0 ? o1 : (blockIdx.z == 1 ? o2 : o3);
    const int tx = threadIdx.x & 31, ty = threadIdx.x >> 5;
    const int r0 = blockIdx.y * 32, c0 = blockIdx.x * 32;
    #pragma unroll
    for (int i = 0; i < 32; i += 8)
        t[ty + i][tx] = in[(size_t)(r0 + ty + i) * CDIM + c0 + tx];
    __syncthreads();
    #pragma unroll
    for (int i = 0; i < 32; i += 8)
        out[(size_t)(c0 + ty + i) * CDIM + r0 + tx] = __float2bfloat16(t[tx][ty + i]);
}

// ---------- fused QV GEMM: [H | V^T] = x @ [W1 | Wv] ----------
// V^T written with sigma-permuted M index (swap bits 2<->3) so the attention
// kernel's PV B-operand lines up with the direct-packed P fragments (no shfl).
__global__ __launch_bounds__(256, 2)
void gemm_qv(const __hip_bfloat16* __restrict__ X, const __hip_bfloat16* __restrict__ W,
             const float* __restrict__ bw1, const float* __restrict__ b1,
             const float* __restrict__ bv, __hip_bfloat16* __restrict__ Hb,
             __hip_bfloat16* __restrict__ Vt, int M)
{
    __shared__ __align__(16) __hip_bfloat16 As[128 * 32];
    __shared__ __align__(16) __hip_bfloat16 Bs[128 * 32];
    const int tid = threadIdx.x, wave = tid >> 6, lane = tid & 63;
    const int wr = wave >> 1, wc = wave & 1, l15 = lane & 15, l4 = lane >> 4;
    const int m0 = blockIdx.y * 128, n0 = blockIdx.x * 128;
    const int K = CDIM;
    const int srow = wave * 32 + (lane >> 2), scol = (lane & 3) * 8;
    const __hip_bfloat16* xg = X + (size_t)(m0 + srow) * K + scol;
    const __hip_bfloat16* wg = W + (size_t)(n0 + srow) * K + scol;
    __hip_bfloat16* la = &As[wave * 32 * 32];
    __hip_bfloat16* lb = &Bs[wave * 32 * 32];

    f32x4 acc[4][4] = {};
    for (int k0 = 0; k0 < K; k0 += 32) {
        __syncthreads();
        gload16(xg + k0, la);
        gload16(xg + k0 + (size_t)16 * K, la + 16 * 32);
        gload16(wg + k0, lb);
        gload16(wg + k0 + (size_t)16 * K, lb + 16 * 32);
        __syncthreads();
        bf16x8 af[4], bfr[4];
        #pragma unroll
        for (int f = 0; f < 4; f++) af[f]  = *(const bf16x8*)&As[(wr * 64 + f * 16 + l15) * 32 + l4 * 8];
        #pragma unroll
        for (int f = 0; f < 4; f++) bfr[f] = *(const bf16x8*)&Bs[(wc * 64 + f * 16 + l15) * 32 + l4 * 8];
        #pragma unroll
        for (int fr = 0; fr < 4; fr++)
            #pragma unroll
            for (int fc = 0; fc < 4; fc++)
                acc[fr][fc] = __builtin_amdgcn_mfma_f32_16x16x32_bf16(af[fr], bfr[fc], acc[fr][fc], 0, 0, 0);
    }

    const bool isH = (n0 < CDIM);
    const int sl4 = ((l4 & 1) << 1) | (l4 >> 1);   // sigma: swap m-bits 2,3
    #pragma unroll
    for (int fc = 0; fc < 4; fc++) {
        const int col = n0 + wc * 64 + fc * 16 + l15;
        if (isH) {
            const float bias = bw1[col] + b1[col & (HS - 1)];
            #pragma unroll
            for (int fr = 0; fr < 4; fr++)
                #pragma unroll
                for (int r = 0; r < 4; r++) {
                    const int row = m0 + wr * 64 + fr * 16 + l4 * 4 + r;
                    Hb[(size_t)row * CDIM + col] = __float2bfloat16(fmaxf(acc[fr][fc][r] + bias, 0.f));
                }
        } else {
            const int c2 = col - CDIM;
            const float bias = bv[c2];
            #pragma unroll
            for (int fr = 0; fr < 4; fr++) {
                const int rowb = m0 + wr * 64 + fr * 16 + sl4 * 4;
                union { ushort4 u; __hip_bfloat16 h[4]; } o;
                #pragma unroll
                for (int r = 0; r < 4; r++) o.h[r] = __float2bfloat16(acc[fr][fc][r] + bias);
                *(ushort4*)(Vt + (size_t)c2 * M + rowb) = o.u;
            }
        }
    }
}

// ---------- projection GEMM: out = Y @ Wp + bp (f32 out) ----------
__global__ __launch_bounds__(256, 2)
void gemm_proj(const __hip_bfloat16* __restrict__ X, const __hip_bfloat16* __restrict__ Wt,
               const float* __restrict__ bN, float* __restrict__ Out, int M)
{
    __shared__ __align__(16) __hip_bfloat16 As[128 * 32];
    __shared__ __align__(16) __hip_bfloat16 Bs[128 * 32];
    const int tid = threadIdx.x, wave = tid >> 6, lane = tid & 63;
    const int wr = wave >> 1, wc = wave & 1, l15 = lane & 15, l4 = lane >> 4;
    const int m0 = blockIdx.y * 128, n0 = blockIdx.x * 128;
    const int K = CDIM;
    const int srow = wave * 32 + (lane >> 2), scol = (lane & 3) * 8;
    const __hip_bfloat16* xg = X + (size_t)(m0 + srow) * K + scol;
    const __hip_bfloat16* wg = Wt + (size_t)(n0 + srow) * K + scol;
    __hip_bfloat16* la = &As[wave * 32 * 32];
    __hip_bfloat16* lb = &Bs[wave * 32 * 32];

    f32x4 acc[4][4] = {};
    for (int k0 = 0; k0 < K; k0 += 32) {
        __syncthreads();
        gload16(xg + k0, la);
        gload16(xg + k0 + (size_t)16 * K, la + 16 * 32);
        gload16(wg + k0, lb);
        gload16(wg + k0 + (size_t)16 * K, lb + 16 * 32);
        __syncthreads();
        bf16x8 af[4], bfr[4];
        #pragma unroll
        for (int f = 0; f < 4; f++) af[f]  = *(const bf16x8*)&As[(wr * 64 + f * 16 + l15) * 32 + l4 * 8];
        #pragma unroll
        for (int f = 0; f < 4; f++) bfr[f] = *(const bf16x8*)&Bs[(wc * 64 + f * 16 + l15) * 32 + l4 * 8];
        #pragma unroll
        for (int fr = 0; fr < 4; fr++)
            #pragma unroll
            for (int fc = 0; fc < 4; fc++)
                acc[fr][fc] = __builtin_amdgcn_mfma_f32_16x16x32_bf16(af[fr], bfr[fc], acc[fr][fc], 0, 0, 0);
    }

    #pragma unroll
    for (int fc = 0; fc < 4; fc++) {
        const int col = n0 + wc * 64 + fc * 16 + l15;
        const float bias = bN[col];
        #pragma unroll
        for (int fr = 0; fr < 4; fr++)
            #pragma unroll
            for (int r = 0; r < 4; r++) {
                const int row = m0 + wr * 64 + fr * 16 + l4 * 4 + r;
                Out[(size_t)row * CDIM + col] = acc[fr][fc][r] + bias;
            }
    }
}

// ---------- fused synthesizer attention v7: k-split x2, 4 waves/SIMD ----------
// Block = 512 threads (8 waves) per (q-pair, sub-group, h, b). Covers q-tiles
// {pi, 15-pi}, 2 subtiles of 32 rows (sub-group sg), 2 k-halves (kt parity).
// wave w -> wl = w<4 ? w : 7-w; tile = wl&1 ? 15-pi : pi; subl = wl>>1;
// half = w>>2. Combine partner = wave 7-w (same q-unit, other k-half) via LDS.
// Per-SIMD work ~17 iters under any wave->SIMD mapping; 4096 waves = 4/SIMD.
__global__ __launch_bounds__(512, 4)
void attn_mfma7(const __hip_bfloat16* __restrict__ H, const __hip_bfloat16* __restrict__ w2t,
                const __hip_bfloat16* __restrict__ Vt, const float* __restrict__ eb2,
                __hip_bfloat16* __restrict__ Y, int M)
{
    __shared__ float LSY[4][2][4][64][4];  // [slot][df][chunk][lane][4]  32 KB
    __shared__ float LSL[4][64];
    __shared__ float Ls[4][32];

    const int tid = threadIdx.x;
    const int w = tid >> 6, lane = tid & 63;
    const int l31 = lane & 31, hi = lane >> 5;
    const int hb = blockIdx.x;
    const int h = hb & 15, b = hb >> 4;
    const int pi = blockIdx.y >> 1, sg = blockIdx.y & 1;
    const int wl = (w < 4) ? w : 7 - w;
    const int half = w >> 2;
    const int qtile = (wl & 1) ? (15 - pi) : pi;
    const int subl = wl >> 1;
    const int qw = qtile * 128 + (sg * 2 + subl) * 32;   // this wave's first q row

    // H fragments (B-operand: col=lane&31=q, k=hi*8+j), in registers
    bf16x8 hf[4];
    {
        const size_t row = (size_t)(b * TSEQ + qw + l31);
        #pragma unroll
        for (int kk = 0; kk < 4; kk++)
            hf[kk] = *(const bf16x8*)(H + row * CDIM + h * HS + kk * 16 + hi * 8);
    }

    // per-lane fragment base pointers
    const __hip_bfloat16* kbase = w2t + (size_t)l31 * HS + hi * 8;
    const __hip_bfloat16* vbase = Vt + (size_t)(h * HS + l31) * M + b * TSEQ + hi * 8;

    f32x16 yacc[2] = {};
    float lsum = 0.f;
    const int lastkt = (qw + 31) >> 6;      // inclusive causal bound

    for (int kt = half; kt <= lastkt; kt += 2) {
        const int k0 = kt * 64;
        const bool nomask = (k0 + 63 <= qw);
        bf16x8 pa[4];
        #pragma unroll
        for (int tf = 0; tf < 2; tf++) {
            float4 eb[4];
            #pragma unroll
            for (int g = 0; g < 4; g++)
                eb[g] = *(const float4*)(eb2 + k0 + tf * 32 + g * 8 + hi * 4);
            f32x16 st = {};
            #pragma unroll
            for (int kk = 0; kk < 4; kk++) {
                bf16x8 kf = *(const bf16x8*)(kbase + (size_t)(k0 + tf * 32) * HS + kk * 16);
                st = __builtin_amdgcn_mfma_f32_32x32x16_bf16(kf, hf[kk], st, 0, 0, 0);
            }
            const int qg = qw + l31;
            float p[16];
            #pragma unroll
            for (int r = 0; r < 16; r++) {
                float e = __expf(st[r]) * ((const float*)&eb[r >> 2])[r & 3];
                if (!nomask) {
                    const int tg = k0 + tf * 32 + (r & 3) + 8 * (r >> 2) + 4 * hi;
                    if (tg > qg) e = 0.f;
                }
                p[r] = e;
                lsum += e;
            }
            // direct pack: A-slot j of chunk ks=2tf+m <- p[8m+j] (sigma'd V aligns)
            #pragma unroll
            for (int m = 0; m < 2; m++) {
                union { unsigned d[4]; bf16x8 v; } pk;
                #pragma unroll
                for (int dw = 0; dw < 4; dw++)
                    pk.d[dw] = packbf(p[8 * m + 2 * dw], p[8 * m + 2 * dw + 1]);
                pa[tf * 2 + m] = pk.v;
            }
        }
        // PV: Y += P @ V_tile (V fragments direct from global)
        #pragma unroll
        for (int ks = 0; ks < 4; ks++) {
            #pragma unroll
            for (int df = 0; df < 2; df++) {
                bf16x8 vf = *(const bf16x8*)(vbase + (size_t)(df * 32) * M + k0 + ks * 16);
                yacc[df] = __builtin_amdgcn_mfma_f32_32x32x16_bf16(pa[ks], vf, yacc[df], 0, 0, 0);
            }
        }
    }

    // ---- k-half combine: upper waves publish, lower waves accumulate ----
    if (half == 1) {
        #pragma unroll
        for (int df = 0; df < 2; df++)
            #pragma unroll
            for (int g = 0; g < 4; g++) {
                float4 t;
                t.x = yacc[df][g * 4 + 0]; t.y = yacc[df][g * 4 + 1];
                t.z = yacc[df][g * 4 + 2]; t.w = yacc[df][g * 4 + 3];
                *(float4*)&LSY[wl][df][g][lane][0] = t;
            }
        LSL[wl][lane] = lsum;
    }
    __syncthreads();
    if (half == 0) {
        lsum += LSL[w][lane];
        #pragma unroll
        for (int df = 0; df < 2; df++)
            #pragma unroll
            for (int g = 0; g < 4; g++) {
                float4 t = *(const float4*)&LSY[w][df][g][lane][0];
                yacc[df][g * 4 + 0] += t.x; yacc[df][g * 4 + 1] += t.y;
                yacc[df][g * 4 + 2] += t.z; yacc[df][g * 4 + 3] += t.w;
            }
        lsum += __shfl_xor(lsum, 32);
        if (hi == 0) Ls[w][l31] = lsum;
    }
    __syncthreads();

    if (half == 0) {
        #pragma unroll
        for (int g = 0; g < 4; g++) {
            float4 lv = *(const float4*)&Ls[w][g * 8 + hi * 4];
            #pragma unroll
            for (int df = 0; df < 2; df++)
                #pragma unroll
                for (int rr = 0; rr < 4; rr++) {
                    const float v = yacc[df][g * 4 + rr] / ((const float*)&lv)[rr];
                    const size_t row = (size_t)(b * TSEQ + qw + 8 * g + 4 * hi + rr);
                    Y[row * CDIM + h * HS + df * 32 + l31] = __float2bfloat16(v);
                }
        }
    }
}

extern "C" void kernel_launch(void* const* d_in, const int* in_sizes, int n_in,
                              void* d_out, int out_size, void* d_ws, size_t ws_size,
                              hipStream_t stream) {
    const float* x   = (const float*)d_in[0];
    const float* W1  = (const float*)d_in[1];
    const float* bw1 = (const float*)d_in[2];
    const float* b1  = (const float*)d_in[3];
    const float* w2  = (const float*)d_in[4];
    const float* b2  = (const float*)d_in[5];
    const float* Wv  = (const float*)d_in[6];
    const float* bv  = (const float*)d_in[7];
    const float* Wp  = (const float*)d_in[8];
    const float* bp  = (const float*)d_in[9];
    float* out = (float*)d_out;

    const int B = in_sizes[0] / (TSEQ * CDIM);   // 2
    const int M = B * TSEQ;                      // 4096
    const size_t MC = (size_t)M * CDIM;          // 4M
    const size_t WC = (size_t)CDIM * CDIM;       // 1M

    __hip_bfloat16* xb  = (__hip_bfloat16*)d_ws;
    __hip_bfloat16* Wqv = xb  + MC;              // [2048][1024]: W1t then Wvt
    __hip_bfloat16* Wpt = Wqv + 2 * WC;
    __hip_bfloat16* w2t = Wpt + WC;              // [T][HS]
    __hip_bfloat16* Hb  = w2t + (size_t)TSEQ * HS;
    __hip_bfloat16* Vtb = Hb  + MC;              // [C][M], sigma-permuted M
    __hip_bfloat16* Yb  = Vtb + MC;
    float*          eb2 = (float*)(Yb + MC);     // exp(b2), T floats

    dim3 blk(256);
    conv_bf16<<<dim3((unsigned)(MC / 1024)), blk, 0, stream>>>(x, xb, (int)MC);
    exp_b2<<<dim3(TSEQ / 256), blk, 0, stream>>>(b2, eb2, TSEQ);
    transpose3_to_bf16<<<dim3(32, 32, 3), blk, 0, stream>>>(W1, Wv, Wp, Wqv, Wqv + WC, Wpt);
    transpose_to_bf16<<<dim3(TSEQ / 32, HS / 32), blk, 0, stream>>>(w2, w2t, HS, TSEQ);

    gemm_qv<<<dim3(16, M / 128), blk, 0, stream>>>(xb, Wqv, bw1, b1, bv, Hb, Vtb, M);

    attn_mfma7<<<dim3(32, 16), dim3(512), 0, stream>>>(Hb, w2t, Vtb, eb2, Yb, M);

    gemm_proj<<<dim3(8, M / 128), blk, 0, stream>>>(Yb, Wpt, bp, out, M);
}